// Round 4
// baseline (84.799 us; speedup 1.0000x reference)
//
#include <hip/hip_runtime.h>
#include <math.h>

#define NQ   16
#define NTH  256
#define NB   512

typedef float2 c32;

__device__ __forceinline__ c32 cmul(c32 a, c32 b) {
    return make_float2(a.x*b.x - a.y*b.y, a.x*b.y + a.y*b.x);
}
__device__ __forceinline__ c32 cfma_(c32 a, c32 b, c32 acc) {
    // acc += a*b
    acc.x = fmaf(a.x, b.x, fmaf(-a.y, b.y, acc.x));
    acc.y = fmaf(a.x, b.y, fmaf( a.y, b.x, acc.y));
    return acc;
}
__device__ __forceinline__ c32 cfmaConjA(c32 a, c32 b, c32 acc) {
    // acc += conj(a)*b
    acc.x = fmaf(a.x, b.x, fmaf( a.y, b.y, acc.x));
    acc.y = fmaf(a.x, b.y, fmaf(-a.y, b.x, acc.y));
    return acc;
}
__device__ __forceinline__ c32 cmulConjA(c32 a, c32 b) {
    return cfmaConjA(a, b, make_float2(0.f, 0.f));
}
__device__ __forceinline__ c32 conjc(c32 a){ return make_float2(a.x, -a.y); }
__device__ __forceinline__ c32 csub(c32 a, c32 b){ return make_float2(a.x-b.x, a.y-b.y); }

// Compact MPS (right-bond top bit == physical index). Envs on 2 diagonal 8x8
// blocks (Hermitian). Sweep: R chain owned entirely by wave 0, L chain by
// wave 1 -> intra-wave lockstep replaces ALL block barriers in the 14-step
// recursion. Register-tiled products (4x2 stage1, 2x2 stage2), Hermitian env
// rows so hot reads are contiguous 8-c32 runs.

__global__ __launch_bounds__(NTH, 2)
void pqc_mps_kernel(const float* __restrict__ ctx,
                    const float* __restrict__ Wm,
                    const float* __restrict__ bias,
                    const float* __restrict__ params,
                    float* __restrict__ out)
{
    __shared__ c32 Ac[14][272];     // sites 1..14; a*17 + i*8 + r
    __shared__ c32 A0c[16];         // i*8 + r
    __shared__ c32 A15v[32];        // a*2 + i
    __shared__ c32 Renv[15][144];   // R_q: m*72 + bl*9 + bp  (wave0-owned in sweep)
    __shared__ c32 Ssto[15][144];   // S_q: i*72 + bl*9 + bp  (wave1-owned)
    __shared__ c32 TRb[272];        // bb*17 + i*8 + gp       (wave0)
    __shared__ c32 TLT[272];        // (i*8+bp)*17 + a        (wave1, transposed)
    __shared__ c32 Lbuf[144];       // running L env          (wave1)
    __shared__ c32 Ug[256];         // fused RZ*RY*RX per (l,q)
    __shared__ c32 wv[64];          // w[q,k,i]
    __shared__ float angles[NQ];

    const int b = blockIdx.x;
    const int t = threadIdx.x;

    // ---- phase A: encoding angles -------------------------------------------
    {
        const int q = t >> 4, g = t & 15;
        const float* crow = ctx + b * 256;
        const float* wrow = Wm + q * 256;
        float s = 0.f;
        #pragma unroll
        for (int j = 0; j < 16; ++j)
            s += crow[g + 16*j] * wrow[g + 16*j];
        #pragma unroll
        for (int m = 8; m; m >>= 1) s += __shfl_xor(s, m);
        if (g == 0) angles[q] = 3.14159265358979323846f * tanhf(s + bias[q]);
    }
    if (t < 64) {  // U = RZ*RY*RX per (l,q)
        const float a  = params[t*3 + 0];
        const float bb = params[t*3 + 1];
        const float c  = params[t*3 + 2];
        const float ha = 0.5f*a, hb = 0.5f*bb, hc = 0.5f*c;
        const float ca = cosf(ha), sa = sinf(ha);
        const float cb = cosf(hb), sb = sinf(hb);
        const float cz = cosf(hc), sz = sinf(hc);
        const c32 m00 = make_float2( cb*ca,  sb*sa);
        const c32 m01 = make_float2(-sb*ca, -cb*sa);
        const c32 m10 = make_float2( sb*ca, -cb*sa);
        const c32 m11 = make_float2( cb*ca, -sb*sa);
        const c32 e0 = make_float2(cz, -sz);
        const c32 e1 = make_float2(cz,  sz);
        Ug[t*4 + 0] = cmul(e0, m00);
        Ug[t*4 + 1] = cmul(e0, m01);
        Ug[t*4 + 2] = cmul(e1, m10);
        Ug[t*4 + 3] = cmul(e1, m11);
    }
    __syncthreads();

    // ---- phase B: w[q,k,i] --------------------------------------------------
    if (t < 64) {
        const int q = t >> 2, k = (t>>1)&1, i = t&1;
        const float h = 0.5f * angles[q];
        const float ch = cosf(h), sh = sinf(h);
        const int r0 = (i ^ k) << 1;
        const c32 u0 = Ug[(q<<2) + r0];
        const c32 u1 = Ug[(q<<2) + r0 + 1];
        wv[t] = make_float2(u0.x*ch + u1.y*sh, u0.y*ch - u1.x*sh);
    }
    __syncthreads();

    // ---- phase C: build compact MPS tensors ---------------------------------
    {
        const int r = t & 7, i = (t>>3)&1, a = t>>4;
        const int m0 = r&1, m1 = (r>>1)&1, m2 = r>>2;
        const int k0 = a&1, k1 = (a>>1)&1, k2 = (a>>2)&1, k3 = a>>3;
        #pragma unroll
        for (int q = 1; q <= 14; ++q) {
            const c32 u3 = Ug[((48+q)<<2) + ((i ^k3)<<1) + m2];
            const c32 u2 = Ug[((32+q)<<2) + ((m2^k2)<<1) + m1];
            const c32 u1 = Ug[((16+q)<<2) + ((m1^k1)<<1) + m0];
            const c32 ww = wv[(q<<2) + (k0<<1) + m0];
            Ac[q-1][a*17 + i*8 + r] = cmul(cmul(u3, u2), cmul(u1, ww));
        }
        if (t < 16) {  // site 0
            const c32 u3 = Ug[(48<<2) + (i <<1) + m2];
            const c32 u2 = Ug[(32<<2) + (m2<<1) + m1];
            const c32 u1 = Ug[(16<<2) + (m1<<1) + m0];
            A0c[t] = cmul(cmul(u3, u2), cmul(u1, wv[m0]));
        }
        if (t >= 64 && t < 96) {  // site 15 dense
            const int idx = t - 64, aa = idx >> 1, ii = idx & 1;
            const int K0 = aa&1, K1 = (aa>>1)&1, K2 = (aa>>2)&1, K3 = aa>>3;
            c32 y1[2], y2[2];
            #pragma unroll
            for (int j1 = 0; j1 < 2; ++j1) {
                const int rr = (j1 ^ K1) << 1;
                y1[j1] = cfma_(Ug[((16+15)<<2)+rr], wv[60 + (K0<<1)],
                         cmul (Ug[((16+15)<<2)+rr+1], wv[60 + (K0<<1) + 1]));
            }
            #pragma unroll
            for (int j2 = 0; j2 < 2; ++j2) {
                const int rr = (j2 ^ K2) << 1;
                y2[j2] = cfma_(Ug[((32+15)<<2)+rr], y1[0],
                         cmul (Ug[((32+15)<<2)+rr+1], y1[1]));
            }
            const int rr = (ii ^ K3) << 1;
            A15v[(aa<<1)+ii] = cfma_(Ug[((48+15)<<2)+rr], y2[0],
                               cmul (Ug[((48+15)<<2)+rr+1], y2[1]));
        }
    }
    __syncthreads();

    // ================= barrier-free sweep: wave0 = R chain, wave1 = L chain ==
    if (t < 64) {
        // ---- wave 0: init R_14, then 14-step R recursion --------------------
        #pragma unroll
        for (int o = 0; o < 2; ++o) {
            const int idx = t + 64*o;
            const int m = idx>>6, bl = (idx>>3)&7, bp = idx&7;
            c32 acc = cmulConjA(A15v[((m<<3)+bl)<<1],       A15v[((m<<3)+bp)<<1]);
            acc     = cfmaConjA(A15v[(((m<<3)+bl)<<1) + 1], A15v[(((m<<3)+bp)<<1) + 1], acc);
            Renv[14][m*72 + bl*9 + bp] = acc;
        }
        if (t < 32) {
            const int bbq = t>>3, i1 = (t>>2)&1, gpp = t&3;     // stage1 role
            const int m2  = t>>4, blp = (t>>2)&3, bpp = t&3;    // stage2 role
            const int bl0 = 2*blp, bp0 = 2*bpp;
            for (int s = 1; s <= 14; ++s) {
                const c32* Ap = Ac[14 - s];   // site 15-s
                // stage1: TR[bb,i,gp] = conj(sum_g Ap[bb,i,g] * Rn[i][gp,g])  (Hermitian Rn)
                {
                    const c32* RnB = Renv[15-s] + i1*72 + (2*gpp)*9;
                    c32 rn0[8], rn1[8];
                    #pragma unroll
                    for (int g = 0; g < 8; ++g) { rn0[g] = RnB[g]; rn1[g] = RnB[9+g]; }
                    #pragma unroll
                    for (int b4 = 0; b4 < 4; ++b4) {
                        const int bb = bbq*4 + b4;
                        const c32* apr = Ap + bb*17 + i1*8;
                        c32 a0 = make_float2(0.f,0.f), a1 = make_float2(0.f,0.f);
                        #pragma unroll
                        for (int g = 0; g < 8; ++g) {
                            const c32 av = apr[g];
                            a0 = cfma_(av, rn0[g], a0);
                            a1 = cfma_(av, rn1[g], a1);
                        }
                        TRb[bb*17 + i1*8 + 2*gpp]     = conjc(a0);
                        TRb[bb*17 + i1*8 + 2*gpp + 1] = conjc(a1);
                    }
                }
                // stage2: R_new[m][bl,bp] = sum_{i,gp} TR[(m,bl),i,gp] * Ap[(m,bp),i,gp]
                {
                    const c32* tr0 = TRb + (m2*8 + bl0)*17;
                    const c32* tr1 = tr0 + 17;
                    const c32* ap0 = Ap + (m2*8 + bp0)*17;
                    const c32* ap1 = ap0 + 17;
                    c32 r00=make_float2(0.f,0.f), r01=r00, r10=r00, r11=r00;
                    #pragma unroll
                    for (int k = 0; k < 16; ++k) {
                        const c32 t0 = tr0[k], t1 = tr1[k];
                        const c32 p0 = ap0[k], p1 = ap1[k];
                        r00 = cfma_(t0, p0, r00); r01 = cfma_(t0, p1, r01);
                        r10 = cfma_(t1, p0, r10); r11 = cfma_(t1, p1, r11);
                    }
                    c32* Ro = Renv[14-s] + m2*72;
                    Ro[ bl0   *9 + bp0] = r00; Ro[ bl0   *9 + bp0+1] = r01;
                    Ro[(bl0+1)*9 + bp0] = r10; Ro[(bl0+1)*9 + bp0+1] = r11;
                }
            }
        }
    } else if (t < 128) {
        // ---- wave 1: init S0/L, then 14-step L recursion --------------------
        const int u = t - 64;
        #pragma unroll
        for (int o = 0; o < 2; ++o) {
            const int idx = u + 64*o;
            const int i = idx>>6, bl = (idx>>3)&7, bp = idx&7;
            const c32 sv = cmulConjA(A0c[(i<<3)+bl], A0c[(i<<3)+bp]);
            Ssto[0][i*72 + bl*9 + bp] = sv;
            Lbuf   [i*72 + bl*9 + bp] = sv;
        }
        if (u < 32) {
            const int aq = u>>3, i1 = (u>>2)&1, bppA = u&3;     // stage1 role
            const int mL = aq>>1, al0 = (aq&1)*4, bp0 = 2*bppA;
            const int i2 = u>>4, blp = (u>>2)&3, bppB = u&3;    // stage2 role
            const int bl0 = 2*blp, bq0 = 2*bppB;
            for (int s = 1; s <= 14; ++s) {
                const c32* As = Ac[s - 1];    // site s
                // stage1: TL[a,i,bp] = sum_g L[m,al,g] * As[(m,g),i,bp]; store transposed
                {
                    c32 lr[4][8];
                    #pragma unroll
                    for (int a4 = 0; a4 < 4; ++a4)
                        #pragma unroll
                        for (int g = 0; g < 8; ++g)
                            lr[a4][g] = Lbuf[mL*72 + (al0+a4)*9 + g];
                    c32 acc[4][2];
                    #pragma unroll
                    for (int a4 = 0; a4 < 4; ++a4) { acc[a4][0] = make_float2(0.f,0.f); acc[a4][1] = make_float2(0.f,0.f); }
                    #pragma unroll
                    for (int g = 0; g < 8; ++g) {
                        const c32 s0 = As[(mL*8+g)*17 + i1*8 + bp0];
                        const c32 s1 = As[(mL*8+g)*17 + i1*8 + bp0 + 1];
                        #pragma unroll
                        for (int a4 = 0; a4 < 4; ++a4) {
                            acc[a4][0] = cfma_(lr[a4][g], s0, acc[a4][0]);
                            acc[a4][1] = cfma_(lr[a4][g], s1, acc[a4][1]);
                        }
                    }
                    #pragma unroll
                    for (int a4 = 0; a4 < 4; ++a4) {
                        TLT[(i1*8 + bp0    )*17 + aq*4 + a4] = acc[a4][0];
                        TLT[(i1*8 + bp0 + 1)*17 + aq*4 + a4] = acc[a4][1];
                    }
                }
                // stage2: S[i][bl,bp] = sum_a conj(As[a,i,bl]) * TLT[(i,bp),a]
                {
                    const c32* tl0 = TLT + (i2*8 + bq0)*17;
                    const c32* tl1 = tl0 + 17;
                    c32 s00=make_float2(0.f,0.f), s01=s00, s10=s00, s11=s00;
                    #pragma unroll
                    for (int a = 0; a < 16; ++a) {
                        const c32 x0 = As[a*17 + i2*8 + bl0];
                        const c32 x1 = As[a*17 + i2*8 + bl0 + 1];
                        const c32 t0 = tl0[a], t1 = tl1[a];
                        s00 = cfmaConjA(x0, t0, s00); s01 = cfmaConjA(x0, t1, s01);
                        s10 = cfmaConjA(x1, t0, s10); s11 = cfmaConjA(x1, t1, s11);
                    }
                    c32* So = Ssto[s] + i2*72;
                    c32* Lo = Lbuf    + i2*72;
                    So[ bl0   *9 + bq0] = s00; So[ bl0   *9 + bq0+1] = s01;
                    So[(bl0+1)*9 + bq0] = s10; So[(bl0+1)*9 + bq0+1] = s11;
                    Lo[ bl0   *9 + bq0] = s00; Lo[ bl0   *9 + bq0+1] = s01;
                    Lo[(bl0+1)*9 + bq0] = s10; Lo[(bl0+1)*9 + bq0+1] = s11;
                }
            }
        }
    }
    __syncthreads();

    // ---- Z phase ------------------------------------------------------------
    {
        const int q = t >> 4, g = t & 15;
        float val = 0.f;
        if (q < 15) {
            const int i = g>>3, bl = g&7;
            const float sign = i ? -1.f : 1.f;
            const c32* Sq = &Ssto[q][i*72 + bl*9];
            const c32* Rq = &Renv[q][i*72 + bl*9];
            #pragma unroll
            for (int j = 0; j < 8; ++j)
                val += sign * (Sq[j].x*Rq[j].x - Sq[j].y*Rq[j].y);
        } else {
            const int m = g>>3, al = g&7;
            const c32 a0 = A15v[((m*8+al)<<1) + 0];
            const c32 a1 = A15v[((m*8+al)<<1) + 1];
            #pragma unroll
            for (int j = 0; j < 8; ++j) {
                c32 d = cmulConjA(a0, A15v[((m*8+j)<<1) + 0]);
                const c32 d1 = cmulConjA(a1, A15v[((m*8+j)<<1) + 1]);
                d.x -= d1.x; d.y -= d1.y;
                const c32 Lv = Lbuf[m*72 + al*9 + j];
                val += Lv.x*d.x - Lv.y*d.y;
            }
        }
        #pragma unroll
        for (int mm = 8; mm; mm >>= 1) val += __shfl_xor(val, mm);
        if (g == 0) out[b*NQ + q] = val;
    }
}

extern "C" void kernel_launch(void* const* d_in, const int* in_sizes, int n_in,
                              void* d_out, int out_size, void* d_ws, size_t ws_size,
                              hipStream_t stream) {
    const float* ctx    = (const float*)d_in[0];   // [512,256]
    const float* Wm     = (const float*)d_in[1];   // [16,256]
    const float* bias   = (const float*)d_in[2];   // [16]
    const float* params = (const float*)d_in[3];   // [4,16,3]
    float* out = (float*)d_out;                    // [512,16]
    (void)in_sizes; (void)n_in; (void)out_size; (void)d_ws; (void)ws_size;
    pqc_mps_kernel<<<NB, NTH, 0, stream>>>(ctx, Wm, bias, params, out);
}

// Round 5
// 78.060 us; speedup vs baseline: 1.0863x; 1.0863x over previous
//
#include <hip/hip_runtime.h>
#include <math.h>

#define NQ   16
#define NTH  256
#define NB   512

typedef float2 c32;

__device__ __forceinline__ c32 cmul(c32 a, c32 b) {
    return make_float2(a.x*b.x - a.y*b.y, a.x*b.y + a.y*b.x);
}
__device__ __forceinline__ c32 cfma_(c32 a, c32 b, c32 acc) {
    // acc += a*b
    acc.x = fmaf(a.x, b.x, fmaf(-a.y, b.y, acc.x));
    acc.y = fmaf(a.x, b.y, fmaf( a.y, b.x, acc.y));
    return acc;
}
__device__ __forceinline__ c32 cfmaConjA(c32 a, c32 b, c32 acc) {
    // acc += conj(a)*b
    acc.x = fmaf(a.x, b.x, fmaf( a.y, b.y, acc.x));
    acc.y = fmaf(a.x, b.y, fmaf(-a.y, b.x, acc.y));
    return acc;
}
__device__ __forceinline__ c32 cmulConjA(c32 a, c32 b) {
    return cfmaConjA(a, b, make_float2(0.f, 0.f));
}
__device__ __forceinline__ c32 conjc(c32 a){ return make_float2(a.x, -a.y); }
__device__ __forceinline__ c32 cadd(c32 a, c32 b){ return make_float2(a.x+b.x, a.y+b.y); }

// Compact MPS (right-bond top bit == physical index). Envs on two diagonal
// 8x8 Hermitian blocks. Sweep: all 256 threads active each phase; R chain on
// waves 0-1, L chain on waves 2-3 (wave-uniform). All read-only site-tensor
// (Ac) operands are PREFETCHED into registers one phase ahead, so their LDS
// latency hides under the barrier wait; only env/stage-1 reads stay on the
// dependent chain.

__global__ __launch_bounds__(NTH, 2)
void pqc_mps_kernel(const float* __restrict__ ctx,
                    const float* __restrict__ Wm,
                    const float* __restrict__ bias,
                    const float* __restrict__ params,
                    float* __restrict__ out)
{
    __shared__ c32 Ac[14][272];     // sites 1..14; a*17 + i*8 + r
    __shared__ c32 A0c[16];         // i*8 + r
    __shared__ c32 A15v[32];        // a*2 + i
    __shared__ c32 Renv[15][144];   // R_q: m*72 + bl*9 + bp
    __shared__ c32 Ssto[15][144];   // S_q: i*72 + bl*9 + bp
    __shared__ c32 TRb[272];        // bb*17 + i*8 + gp
    __shared__ c32 TLT[272];        // (i*8+bp)*17 + a   (transposed stage-1 L)
    __shared__ c32 Lbuf[144];       // running L env
    __shared__ c32 Ug[256];         // fused RZ*RY*RX per (l,q)
    __shared__ c32 wv[64];          // w[q,k,i]
    __shared__ float angles[NQ];

    const int b = blockIdx.x;
    const int t = threadIdx.x;

    // ---- phase A: encoding angles -------------------------------------------
    {
        const int q = t >> 4, g = t & 15;
        const float* crow = ctx + b * 256;
        const float* wrow = Wm + q * 256;
        float s = 0.f;
        #pragma unroll
        for (int j = 0; j < 16; ++j)
            s += crow[g + 16*j] * wrow[g + 16*j];
        #pragma unroll
        for (int m = 8; m; m >>= 1) s += __shfl_xor(s, m);
        if (g == 0) angles[q] = 3.14159265358979323846f * tanhf(s + bias[q]);
    }
    if (t < 64) {  // U = RZ*RY*RX per (l,q)
        const float a  = params[t*3 + 0];
        const float bb = params[t*3 + 1];
        const float c  = params[t*3 + 2];
        const float ha = 0.5f*a, hb = 0.5f*bb, hc = 0.5f*c;
        const float ca = cosf(ha), sa = sinf(ha);
        const float cb = cosf(hb), sb = sinf(hb);
        const float cz = cosf(hc), sz = sinf(hc);
        const c32 m00 = make_float2( cb*ca,  sb*sa);
        const c32 m01 = make_float2(-sb*ca, -cb*sa);
        const c32 m10 = make_float2( sb*ca, -cb*sa);
        const c32 m11 = make_float2( cb*ca, -sb*sa);
        const c32 e0 = make_float2(cz, -sz);
        const c32 e1 = make_float2(cz,  sz);
        Ug[t*4 + 0] = cmul(e0, m00);
        Ug[t*4 + 1] = cmul(e0, m01);
        Ug[t*4 + 2] = cmul(e1, m10);
        Ug[t*4 + 3] = cmul(e1, m11);
    }
    __syncthreads();

    // ---- phase B: w[q,k,i] --------------------------------------------------
    if (t < 64) {
        const int q = t >> 2, k = (t>>1)&1, i = t&1;
        const float h = 0.5f * angles[q];
        const float ch = cosf(h), sh = sinf(h);
        const int r0 = (i ^ k) << 1;
        const c32 u0 = Ug[(q<<2) + r0];
        const c32 u1 = Ug[(q<<2) + r0 + 1];
        wv[t] = make_float2(u0.x*ch + u1.y*sh, u0.y*ch - u1.x*sh);
    }
    __syncthreads();

    // ---- phase C: build compact MPS tensors ---------------------------------
    {
        const int r = t & 7, i = (t>>3)&1, a = t>>4;
        const int m0 = r&1, m1 = (r>>1)&1, m2 = r>>2;
        const int k0 = a&1, k1 = (a>>1)&1, k2 = (a>>2)&1, k3 = a>>3;
        #pragma unroll
        for (int q = 1; q <= 14; ++q) {
            const c32 u3 = Ug[((48+q)<<2) + ((i ^k3)<<1) + m2];
            const c32 u2 = Ug[((32+q)<<2) + ((m2^k2)<<1) + m1];
            const c32 u1 = Ug[((16+q)<<2) + ((m1^k1)<<1) + m0];
            const c32 ww = wv[(q<<2) + (k0<<1) + m0];
            Ac[q-1][a*17 + i*8 + r] = cmul(cmul(u3, u2), cmul(u1, ww));
        }
        if (t < 16) {  // site 0
            const c32 u3 = Ug[(48<<2) + (i <<1) + m2];
            const c32 u2 = Ug[(32<<2) + (m2<<1) + m1];
            const c32 u1 = Ug[(16<<2) + (m1<<1) + m0];
            A0c[t] = cmul(cmul(u3, u2), cmul(u1, wv[m0]));
        }
        if (t >= 64 && t < 96) {  // site 15 dense
            const int idx = t - 64, aa = idx >> 1, ii = idx & 1;
            const int K0 = aa&1, K1 = (aa>>1)&1, K2 = (aa>>2)&1, K3 = aa>>3;
            c32 y1[2], y2[2];
            #pragma unroll
            for (int j1 = 0; j1 < 2; ++j1) {
                const int rr = (j1 ^ K1) << 1;
                y1[j1] = cfma_(Ug[((16+15)<<2)+rr], wv[60 + (K0<<1)],
                         cmul (Ug[((16+15)<<2)+rr+1], wv[60 + (K0<<1) + 1]));
            }
            #pragma unroll
            for (int j2 = 0; j2 < 2; ++j2) {
                const int rr = (j2 ^ K2) << 1;
                y2[j2] = cfma_(Ug[((32+15)<<2)+rr], y1[0],
                         cmul (Ug[((32+15)<<2)+rr+1], y1[1]));
            }
            const int rr = (ii ^ K3) << 1;
            A15v[(aa<<1)+ii] = cfma_(Ug[((48+15)<<2)+rr], y2[0],
                               cmul (Ug[((48+15)<<2)+rr+1], y2[1]));
        }
    }
    __syncthreads();

    // ---- thread-role constants for the sweep --------------------------------
    // phase1-R (t<128): output TR[bb, i, gp0..gp0+1]
    const int bbR = t >> 3, iR = (t >> 2) & 1, gp0 = (t & 3) * 2;
    // phase1-L (t>=128): output TL[aL, i, bp0..bp0+1]
    const int uL = t - 128;
    const int aL = uL >> 3, iL = (uL >> 2) & 1, bp0 = (uL & 3) * 2;
    const int mL = aL >> 3, alL = aL & 7;
    // phase2 (both halves): one output (m/i, bl, bp)
    const int m2 = (t >> 6) & 1, bl2 = (t >> 3) & 7, bp2 = t & 7;
    const int i2L = uL >> 6;   // valid for t>=128

    c32 aP1[8], sA0[8], sA1[8], pf2[16];

    // ---- init step 0 + prologue prefetch (s=1) ------------------------------
    if (t < 128) {
        const int m = t>>6, bl = (t>>3)&7, bp = t&7;
        c32 acc = cmulConjA(A15v[((m<<3)+bl)<<1],       A15v[((m<<3)+bp)<<1]);
        acc     = cfmaConjA(A15v[(((m<<3)+bl)<<1) + 1], A15v[(((m<<3)+bp)<<1) + 1], acc);
        Renv[14][m*72 + bl*9 + bp] = acc;
        const c32* Ap = Ac[13];               // site 14 = Ap for s=1
        #pragma unroll
        for (int g = 0; g < 8; ++g) aP1[g] = Ap[bbR*17 + iR*8 + g];
    } else {
        const int i = uL>>6, bl = (uL>>3)&7, bp = uL&7;
        const c32 sv = cmulConjA(A0c[(i<<3)+bl], A0c[(i<<3)+bp]);
        Ssto[0][i*72 + bl*9 + bp] = sv;
        Lbuf   [i*72 + bl*9 + bp] = sv;
        const c32* As = Ac[0];                // site 1 = As for s=1
        #pragma unroll
        for (int g = 0; g < 8; ++g) {
            sA0[g] = As[(mL*8+g)*17 + iL*8 + bp0];
            sA1[g] = As[(mL*8+g)*17 + iL*8 + bp0 + 1];
        }
    }
    __syncthreads();

    // ---- merged sweep: R chain (waves 0-1) and L chain (waves 2-3) ----------
    for (int s = 1; s <= 14; ++s) {
        const c32* Ap = Ac[14 - s];   // site 15-s
        const c32* As = Ac[s - 1];    // site s

        if (t < 128) {
            // phase1-R: TR[bb,i,gp] = conj( sum_g Ap[bb,i,g] * Rn[i][gp,g] )
            const c32* RnB = Renv[15-s] + iR*72 + gp0*9;
            c32 x0 = make_float2(0.f,0.f), x1 = x0;
            #pragma unroll
            for (int g = 0; g < 8; ++g) {
                x0 = cfma_(aP1[g], RnB[g],   x0);
                x1 = cfma_(aP1[g], RnB[9+g], x1);
            }
            TRb[bbR*17 + iR*8 + gp0]     = conjc(x0);
            TRb[bbR*17 + iR*8 + gp0 + 1] = conjc(x1);
            // prefetch phase2-R A row (independent of TR)
            #pragma unroll
            for (int k = 0; k < 16; ++k) pf2[k] = Ap[(m2*8+bp2)*17 + k];
        } else {
            // phase1-L: TL[a,i,bp] = sum_g L[m][al,g] * As[(m,g),i,bp]
            const c32* Lr = Lbuf + mL*72 + alL*9;
            c32 x0 = make_float2(0.f,0.f), x1 = x0;
            #pragma unroll
            for (int g = 0; g < 8; ++g) {
                const c32 lv = Lr[g];
                x0 = cfma_(lv, sA0[g], x0);
                x1 = cfma_(lv, sA1[g], x1);
            }
            TLT[(iL*8 + bp0    )*17 + aL] = x0;
            TLT[(iL*8 + bp0 + 1)*17 + aL] = x1;
            // prefetch phase2-L A column (independent of TLT)
            #pragma unroll
            for (int k = 0; k < 16; ++k) pf2[k] = As[k*17 + i2L*8 + bl2];
        }
        __syncthreads();

        if (t < 128) {
            // phase2-R: R_new[m][bl,bp] = sum_k TR[(m,bl),k] * Ap[(m,bp),k]
            const c32* trR = TRb + (m2*8 + bl2)*17;
            c32 r0 = make_float2(0.f,0.f), r1 = r0;
            #pragma unroll
            for (int k = 0; k < 16; k += 2) {
                r0 = cfma_(trR[k],   pf2[k],   r0);
                r1 = cfma_(trR[k+1], pf2[k+1], r1);
            }
            Renv[14-s][m2*72 + bl2*9 + bp2] = cadd(r0, r1);
            if (s < 14) {   // prefetch phase1-R A row for s+1 (site 14-s)
                const c32* ApN = Ac[13 - s];
                #pragma unroll
                for (int g = 0; g < 8; ++g) aP1[g] = ApN[bbR*17 + iR*8 + g];
            }
        } else {
            // phase2-L: S[i][bl,bp] = sum_a conj(As[a,i,bl]) * TLT[(i,bp),a]
            const c32* tlR = TLT + (i2L*8 + bp2)*17;
            c32 s0 = make_float2(0.f,0.f), s1 = s0;
            #pragma unroll
            for (int k = 0; k < 16; k += 2) {
                s0 = cfmaConjA(pf2[k],   tlR[k],   s0);
                s1 = cfmaConjA(pf2[k+1], tlR[k+1], s1);
            }
            const c32 sv = cadd(s0, s1);
            Ssto[s][i2L*72 + bl2*9 + bp2] = sv;
            Lbuf   [i2L*72 + bl2*9 + bp2] = sv;
            if (s < 14) {   // prefetch phase1-L A rows for s+1 (site s+1)
                const c32* AsN = Ac[s];
                #pragma unroll
                for (int g = 0; g < 8; ++g) {
                    sA0[g] = AsN[(mL*8+g)*17 + iL*8 + bp0];
                    sA1[g] = AsN[(mL*8+g)*17 + iL*8 + bp0 + 1];
                }
            }
        }
        __syncthreads();
    }

    // ---- Z phase ------------------------------------------------------------
    {
        const int q = t >> 4, g = t & 15;
        float val = 0.f;
        if (q < 15) {
            const int i = g>>3, bl = g&7;
            const float sign = i ? -1.f : 1.f;
            const c32* Sq = &Ssto[q][i*72 + bl*9];
            const c32* Rq = &Renv[q][i*72 + bl*9];
            #pragma unroll
            for (int j = 0; j < 8; ++j)
                val += sign * (Sq[j].x*Rq[j].x - Sq[j].y*Rq[j].y);
        } else {
            const int m = g>>3, al = g&7;
            const c32 a0 = A15v[((m*8+al)<<1) + 0];
            const c32 a1 = A15v[((m*8+al)<<1) + 1];
            #pragma unroll
            for (int j = 0; j < 8; ++j) {
                c32 d = cmulConjA(a0, A15v[((m*8+j)<<1) + 0]);
                const c32 d1 = cmulConjA(a1, A15v[((m*8+j)<<1) + 1]);
                d.x -= d1.x; d.y -= d1.y;
                const c32 Lv = Lbuf[m*72 + al*9 + j];
                val += Lv.x*d.x - Lv.y*d.y;
            }
        }
        #pragma unroll
        for (int mm = 8; mm; mm >>= 1) val += __shfl_xor(val, mm);
        if (g == 0) out[b*NQ + q] = val;
    }
}

extern "C" void kernel_launch(void* const* d_in, const int* in_sizes, int n_in,
                              void* d_out, int out_size, void* d_ws, size_t ws_size,
                              hipStream_t stream) {
    const float* ctx    = (const float*)d_in[0];   // [512,256]
    const float* Wm     = (const float*)d_in[1];   // [16,256]
    const float* bias   = (const float*)d_in[2];   // [16]
    const float* params = (const float*)d_in[3];   // [4,16,3]
    float* out = (float*)d_out;                    // [512,16]
    (void)in_sizes; (void)n_in; (void)out_size; (void)d_ws; (void)ws_size;
    pqc_mps_kernel<<<NB, NTH, 0, stream>>>(ctx, Wm, bias, params, out);
}